// Round 19
// baseline (278.253 us; speedup 1.0000x reference)
//
#include <hip/hip_runtime.h>
#include <stdint.h>

// SpatialHyperedgeMP: out = ((inc + head) @ cur) / rowsum(inc + head)
//   head_ij = (inc_ij > 0) / sqrt(cnt_i),  cnt_i = #positives in row i
//
// R19: PRE-TRANSFORMED OPERAND pipeline (with ws fallback to R11).
//   R5-R18 showed the fused dual-GEMM plateaus at ~167us (stall-bound, all
//   pipes <50%). R16 showed the single GEMM is ~35% faster but its separate
//   stats pass (43us) ate the win. Fix: the stats pass now ALSO writes
//   A' = bf16(inc + mask*invs) to ws in pre-swizzled MFMA fragment chunks
//   (reg-cached: reads inc ONCE). The GEMM then needs no LDS, no barriers,
//   no XFORM, no stats: A'/B fragments stream directly into registers with
//   full-cluster prefetch; epilogue scales by rdeg.
//   ws layout: B chunks @0 (8MB) | rdeg @8388608 (32KB) | A' @8421376 (128MB).
//   If ws_size < 142,639,104: fall back to the proven R11 pipeline (167us).

#define NROWS 8192
#define DDIM  512

typedef float f32x4 __attribute__((ext_vector_type(4)));
typedef short s16x8 __attribute__((ext_vector_type(8)));

__device__ __forceinline__ unsigned short f2bf(float f) {
  union { float f; unsigned int u; } c; c.f = f;
  unsigned int u = c.u;
  unsigned int r = u + 0x7FFFu + ((u >> 16) & 1u);
  return (unsigned short)(r >> 16);
}

// ---------------- kernel: B prep (cur -> bf16 chunked-transposed) ----------------
// chunk layout: nt(2) x kt(128): 32KB chunk = [kg=8][nn=256][e=8] bf16
__global__ __launch_bounds__(256) void bprep_kernel(const float* __restrict__ cur,
                                                    unsigned char* __restrict__ bws) {
  int idx = blockIdx.x * 256 + threadIdx.x;  // 0..524287
  int n = idx & 511;
  int kg9 = idx >> 9;  // 0..1023
  int kt = kg9 >> 3;
  int kg = kg9 & 7;
  int k0 = kt * 64 + kg * 8;
  union { unsigned short h[8]; uint4 q; } u;
#pragma unroll
  for (int e = 0; e < 8; ++e)
    u.h[e] = f2bf(cur[(size_t)(k0 + e) * DDIM + n]);
  int nt = n >> 8, nn = n & 255;
  size_t off = ((size_t)(nt * 128 + kt) << 15) + ((size_t)kg << 12) + ((size_t)nn << 4);
  *(uint4*)(bws + off) = u.q;
}

// ---------------- kernel: stats + A' pre-transform (fast path) ----------------
// Grid 2048 x 1024 thr; block b handles rows b*4..b*4+3; thread (rr=tid>>8,
// c=tid&255) owns row b*4+rr, k in [c*32, c*32+32), cached in 8 f32x4 regs.
// Writes rdeg[row] and A' chunks: (mt,kt) 4KB = [kg=8][slot=32][e=8] bf16,
// slot = rowIn ^ kg (same fragment layout the GEMM reads).
__global__ __launch_bounds__(1024) void prep_kernel(const float* __restrict__ inc,
                                                    float* __restrict__ rdeg,
                                                    unsigned char* __restrict__ aprime) {
  const int b = blockIdx.x;          // 0..2047
  const int tid = threadIdx.x;
  const int rr = tid >> 8;           // 0..3 (row within quad; waves row-aligned)
  const int c = tid & 255;           // k-chunk: k = c*32..c*32+31
  const int row = b * 4 + rr;

  const f32x4* p = (const f32x4*)(inc + (size_t)row * NROWS + c * 32);
  f32x4 f0 = p[0], f1 = p[1], f2 = p[2], f3 = p[3];
  f32x4 f4 = p[4], f5 = p[5], f6 = p[6], f7 = p[7];

  double s = 0.0;
  int cnt = 0;
#define STAT(v) do {                                                                      \
    s += (double)v[0] + (double)v[1] + (double)v[2] + (double)v[3];                       \
    cnt += (v[0] > 0.f) + (v[1] > 0.f) + (v[2] > 0.f) + (v[3] > 0.f);                     \
  } while (0)
  STAT(f0); STAT(f1); STAT(f2); STAT(f3); STAT(f4); STAT(f5); STAT(f6); STAT(f7);
#undef STAT

  // wave reduce (each wave = one row)
#pragma unroll
  for (int o = 1; o < 64; o <<= 1) {
    s += __shfl_xor(s, o);
    cnt += __shfl_xor(cnt, o);
  }
  __shared__ double sws[16];
  __shared__ int cws[16];
  __shared__ float invS[4];
  const int wv = tid >> 6, lane = tid & 63;
  if (lane == 0) { sws[wv] = s; cws[wv] = cnt; }
  __syncthreads();
  if (tid < 4) {
    double S = sws[tid * 4] + sws[tid * 4 + 1] + sws[tid * 4 + 2] + sws[tid * 4 + 3];
    int C = cws[tid * 4] + cws[tid * 4 + 1] + cws[tid * 4 + 2] + cws[tid * 4 + 3];
    double sq = sqrt((double)C);
    invS[tid] = (C > 0) ? (float)(1.0 / sq) : 0.0f;
    rdeg[b * 4 + tid] = (float)(1.0 / (S + sq));
  }
  __syncthreads();
  const float invr = invS[rr];

  // write A' = bf16(v + (v>0)*invr) into chunk (mt, kt = c>>1)
  const int mt = row >> 5, rowIn = row & 31;
  const int kt = c >> 1;
  const int kgBase = (c & 1) * 4;
  unsigned char* chunk = aprime + (((size_t)mt * 128 + kt) << 12);
#define EMIT(lo, hi, I) do {                                                              \
    int kg = kgBase + (I);                                                                \
    float a0 = lo[0] + (lo[0] > 0.f ? invr : 0.f);                                        \
    float a1 = lo[1] + (lo[1] > 0.f ? invr : 0.f);                                        \
    float a2 = lo[2] + (lo[2] > 0.f ? invr : 0.f);                                        \
    float a3 = lo[3] + (lo[3] > 0.f ? invr : 0.f);                                        \
    float a4 = hi[0] + (hi[0] > 0.f ? invr : 0.f);                                        \
    float a5 = hi[1] + (hi[1] > 0.f ? invr : 0.f);                                        \
    float a6 = hi[2] + (hi[2] > 0.f ? invr : 0.f);                                        \
    float a7 = hi[3] + (hi[3] > 0.f ? invr : 0.f);                                        \
    uint4 w;                                                                              \
    asm("v_cvt_pk_bf16_f32 %0, %1, %2" : "=v"(w.x) : "v"(a0), "v"(a1));                   \
    asm("v_cvt_pk_bf16_f32 %0, %1, %2" : "=v"(w.y) : "v"(a2), "v"(a3));                   \
    asm("v_cvt_pk_bf16_f32 %0, %1, %2" : "=v"(w.z) : "v"(a4), "v"(a5));                   \
    asm("v_cvt_pk_bf16_f32 %0, %1, %2" : "=v"(w.w) : "v"(a6), "v"(a7));                   \
    *(uint4*)(chunk + (kg << 9) + ((rowIn ^ kg) << 4)) = w;                               \
  } while (0)
  EMIT(f0, f1, 0);
  EMIT(f2, f3, 1);
  EMIT(f4, f5, 2);
  EMIT(f6, f7, 3);
#undef EMIT
}

// ---------------- kernel: dataflow GEMM (fast path) ----------------
// BM=32 BN=256 BK=64, 512 thr = 8 waves (1M x 8N), wave tile 32x32.
// NO LDS, NO barriers: A'/B fragments stream ws->regs, full-cluster prefetch.
#define FENCE() __builtin_amdgcn_sched_barrier(0)
#define MFMA_ __builtin_amdgcn_mfma_f32_16x16x32_bf16

__global__ __launch_bounds__(512, 4) void gemm_fast(const unsigned char* __restrict__ aprime,
                                                    const unsigned char* __restrict__ bws,
                                                    const float* __restrict__ rdeg,
                                                    float* __restrict__ out) {
  const int tid = threadIdx.x;
  const int lane = tid & 63;
  const int wv = tid >> 6;       // 0..7 column group
  const int r = lane & 15;
  const int q = lane >> 4;       // 0..3

  const int id = blockIdx.x;     // 0..511
  const int nt = (id & 7) >> 2;  // XCD half -> fixed 4MB B chunk per XCD L2
  const int mt = (id >> 3) * 4 + (id & 3);   // 0..255; partners id,id^4 adjacent
  const int brow = mt * 32;

  const unsigned char* gA = aprime + ((size_t)mt << 19);   // mt * 128 chunks * 4KB
  const unsigned char* gB = bws + ((size_t)(nt * 128) << 15);

  int aOff[4];  // [kh*2+rg]
  int bOff[4];  // [kh*2+cg]
#pragma unroll
  for (int kh = 0; kh < 2; ++kh)
#pragma unroll
    for (int g = 0; g < 2; ++g) {
      int kg = kh * 4 + q;
      int row = g * 16 + r;
      aOff[kh * 2 + g] = (kg << 9) + ((row ^ kg) << 4);
      bOff[kh * 2 + g] = (kg << 12) + ((wv * 32 + g * 16 + r) << 4);
    }

  f32x4 acc[2][2];
#pragma unroll
  for (int a = 0; a < 2; ++a)
#pragma unroll
    for (int b = 0; b < 2; ++b)
      acc[a][b] = (f32x4){0.f, 0.f, 0.f, 0.f};

  s16x8 aX[4], aY[4], bX[4], bY[4];

#define LOADA(S, KT) do {                                                                 \
    const unsigned char* _g = gA + ((size_t)(KT) << 12);                                  \
    S[0] = *(const s16x8*)(_g + aOff[0]);                                                 \
    S[1] = *(const s16x8*)(_g + aOff[1]);                                                 \
    S[2] = *(const s16x8*)(_g + aOff[2]);                                                 \
    S[3] = *(const s16x8*)(_g + aOff[3]);                                                 \
  } while (0)

#define LOADB(S, KT) do {                                                                 \
    const unsigned char* _g = gB + ((size_t)(KT) << 15);                                  \
    S[0] = *(const s16x8*)(_g + bOff[0]);                                                 \
    S[1] = *(const s16x8*)(_g + bOff[1]);                                                 \
    S[2] = *(const s16x8*)(_g + bOff[2]);                                                 \
    S[3] = *(const s16x8*)(_g + bOff[3]);                                                 \
  } while (0)

#define MFMA_TILE(A, B) do {                                                              \
    __builtin_amdgcn_s_setprio(1);                                                        \
    _Pragma("unroll")                                                                     \
    for (int kh = 0; kh < 2; ++kh) {                                                      \
      acc[0][0] = MFMA_(A[kh * 2 + 0], B[kh * 2 + 0], acc[0][0], 0, 0, 0);                \
      acc[0][1] = MFMA_(A[kh * 2 + 0], B[kh * 2 + 1], acc[0][1], 0, 0, 0);                \
      acc[1][0] = MFMA_(A[kh * 2 + 1], B[kh * 2 + 0], acc[1][0], 0, 0, 0);                \
      acc[1][1] = MFMA_(A[kh * 2 + 1], B[kh * 2 + 1], acc[1][1], 0, 0, 0);                \
    }                                                                                     \
    __builtin_amdgcn_s_setprio(0);                                                        \
  } while (0)

  // prologue
  LOADA(aX, 0);
  LOADB(bX, 0);
  // steady: issue next tile's 8 loads before this tile's MFMAs (full-cluster cover)
  for (int kt = 0; kt < 126; kt += 2) {
    LOADA(aY, kt + 1);
    LOADB(bY, kt + 1);
    FENCE();
    MFMA_TILE(aX, bX);        // auto-wait retires X loads only; Y rides
    LOADA(aX, kt + 2);
    LOADB(bX, kt + 2);
    FENCE();
    MFMA_TILE(aY, bY);
  }
  LOADA(aY, 127);
  LOADB(bY, 127);
  FENCE();
  MFMA_TILE(aX, bX);          // tile 126
  MFMA_TILE(aY, bY);          // tile 127

  // epilogue: * rdeg (L1-cached; 32 values shared by the block)
#pragma unroll
  for (int rg = 0; rg < 2; ++rg)
#pragma unroll
    for (int cg = 0; cg < 2; ++cg)
#pragma unroll
      for (int j = 0; j < 4; ++j) {
        int row = rg * 16 + q * 4 + j;
        out[(size_t)(brow + row) * DDIM + nt * 256 + wv * 32 + cg * 16 + r] =
            acc[rg][cg][j] * rdeg[brow + row];
      }
#undef LOADA
#undef LOADB
#undef MFMA_TILE
}

// ---------------- fallback: R11 fused dual-GEMM (best proven: 167us) ----------------
#define BARRIER() __builtin_amdgcn_s_barrier()
#define WAITLGKM() asm volatile("s_waitcnt lgkmcnt(0)" ::: "memory")

__global__ __launch_bounds__(512, 4) void gemm_dual(const float* __restrict__ inc,
                                                    const unsigned char* __restrict__ bws,
                                                    float* __restrict__ out) {
  __shared__ __align__(16) unsigned char smem[16512];
  unsigned char* const buf0 = smem;
  unsigned char* const buf1 = smem + 8192;

  const int tid = threadIdx.x;
  const int lane = tid & 63;
  const int wv = tid >> 6;
  const int r = lane & 15;
  const int q = lane >> 4;

  const int id = blockIdx.x;
  const int nt = (id & 7) >> 2;
  const int mt = (id >> 3) * 4 + (id & 3);
  const int brow = mt * 32;

  const int sm = tid >> 4;
  const int sp = tid & 15;
  const int kgw = sp >> 1, half = sp & 1;
  const float4* gAr = (const float4*)(inc + (size_t)(brow + sm) * NROWS) + sp;
  const int aWr = (kgw << 9) + ((sm ^ kgw) << 4) + (half << 3);

  int aOff[2][2];
#pragma unroll
  for (int kh = 0; kh < 2; ++kh)
#pragma unroll
    for (int rg = 0; rg < 2; ++rg) {
      int kg = kh * 4 + q;
      int row = rg * 16 + r;
      aOff[kh][rg] = (kg << 9) + ((row ^ kg) << 4);
    }

  const unsigned char* gB = bws + ((size_t)(nt * 128) << 15);
  int bOff[4];
#pragma unroll
  for (int kh = 0; kh < 2; ++kh)
#pragma unroll
    for (int cg = 0; cg < 2; ++cg)
      bOff[kh * 2 + cg] = ((kh * 4 + q) << 12) + ((wv * 32 + cg * 16 + r) << 4);

  f32x4 acc1[2][2], acc2[2][2];
#pragma unroll
  for (int a = 0; a < 2; ++a)
#pragma unroll
    for (int b = 0; b < 2; ++b) {
      acc1[a][b] = (f32x4){0.f, 0.f, 0.f, 0.f};
      acc2[a][b] = (f32x4){0.f, 0.f, 0.f, 0.f};
    }

  double s1 = 0.0;
  int cnt = 0;
  float4 x, y;
  s16x8 bX[4], bY[4];

#define ISSUE_A(d, KT) do { d = gAr[(KT) * 16]; } while (0)
#define LOADB2(BS, KT) do {                                                               \
    const unsigned char* _g = gB + ((size_t)(KT) << 15);                                  \
    BS[0] = *(const s16x8*)(_g + bOff[0]);                                                \
    BS[1] = *(const s16x8*)(_g + bOff[1]);                                                \
    BS[2] = *(const s16x8*)(_g + bOff[2]);                                                \
    BS[3] = *(const s16x8*)(_g + bOff[3]);                                                \
  } while (0)
#define XFORM(v, BUF) do {                                                                \
    s1 += (double)v.x + (double)v.y + (double)v.z + (double)v.w;                          \
    cnt += (v.x > 0.f) + (v.y > 0.f) + (v.z > 0.f) + (v.w > 0.f);                         \
    unsigned dlo, dhi;                                                                    \
    asm("v_cvt_pk_bf16_f32 %0, %1, %2" : "=v"(dlo) : "v"(v.x), "v"(v.y));                 \
    asm("v_cvt_pk_bf16_f32 %0, %1, %2" : "=v"(dhi) : "v"(v.z), "v"(v.w));                 \
    unsigned mlo = (v.x > 0.f ? 0x3F80u : 0u) | (v.y > 0.f ? 0x3F800000u : 0u);           \
    unsigned mhi = (v.z > 0.f ? 0x3F80u : 0u) | (v.w > 0.f ? 0x3F800000u : 0u);           \
    *(unsigned long long*)((BUF) + aWr) =                                                 \
        (unsigned long long)dlo | ((unsigned long long)dhi << 32);                        \
    *(unsigned long long*)((BUF) + 4096 + aWr) =                                          \
        (unsigned long long)mlo | ((unsigned long long)mhi << 32);                        \
  } while (0)
#define MFMA_TILE2(BUF, BS) do {                                                          \
    _Pragma("unroll")                                                                     \
    for (int kh = 0; kh < 2; ++kh) {                                                      \
      s16x8 af0 = *(const s16x8*)((BUF) + aOff[kh][0]);                                   \
      s16x8 af1 = *(const s16x8*)((BUF) + aOff[kh][1]);                                   \
      s16x8 mf0 = *(const s16x8*)((BUF) + 4096 + aOff[kh][0]);                            \
      s16x8 mf1 = *(const s16x8*)((BUF) + 4096 + aOff[kh][1]);                            \
      __builtin_amdgcn_s_setprio(1);                                                      \
      acc1[0][0] = MFMA_(af0, BS[kh * 2 + 0], acc1[0][0], 0, 0, 0);                       \
      acc2[0][0] = MFMA_(mf0, BS[kh * 2 + 0], acc2[0][0], 0, 0, 0);                       \
      acc1[0][1] = MFMA_(af0, BS[kh * 2 + 1], acc1[0][1], 0, 0, 0);                       \
      acc2[0][1] = MFMA_(mf0, BS[kh * 2 + 1], acc2[0][1], 0, 0, 0);                       \
      acc1[1][0] = MFMA_(af1, BS[kh * 2 + 0], acc1[1][0], 0, 0, 0);                       \
      acc2[1][0] = MFMA_(mf1, BS[kh * 2 + 0], acc2[1][0], 0, 0, 0);                       \
      acc1[1][1] = MFMA_(af1, BS[kh * 2 + 1], acc1[1][1], 0, 0, 0);                       \
      acc2[1][1] = MFMA_(mf1, BS[kh * 2 + 1], acc2[1][1], 0, 0, 0);                       \
      __builtin_amdgcn_s_setprio(0);                                                      \
    }                                                                                     \
  } while (0)
#define SYNC() do { FENCE(); WAITLGKM(); FENCE(); BARRIER(); FENCE(); } while (0)

  ISSUE_A(x, 0);
  LOADB2(bX, 0);
  ISSUE_A(y, 1);
  XFORM(x, buf0);
  SYNC();
  for (int kt = 0; kt < 126; kt += 2) {
    ISSUE_A(x, kt + 2);
    LOADB2(bY, kt + 1);
    FENCE();
    MFMA_TILE2(buf0, bX);
    XFORM(y, buf1);
    SYNC();
    ISSUE_A(y, kt + 3);
    LOADB2(bX, kt + 2);
    FENCE();
    MFMA_TILE2(buf1, bY);
    XFORM(x, buf0);
    SYNC();
  }
  LOADB2(bY, 127);
  FENCE();
  MFMA_TILE2(buf0, bX);
  XFORM(y, buf1);
  SYNC();
  MFMA_TILE2(buf1, bY);

#pragma unroll
  for (int o = 1; o < 16; o <<= 1) {
    s1 += __shfl_xor(s1, o);
    cnt += __shfl_xor(cnt, o);
  }
  __syncthreads();
  float* const invsS = (float*)buf0;
  float* const rdegS = invsS + 32;
  if (sp == 0) {
    double sq = sqrt((double)cnt);
    invsS[sm] = (cnt > 0) ? (float)(1.0 / sq) : 0.0f;
    rdegS[sm] = (float)(1.0 / (s1 + sq));
  }
  __syncthreads();

#pragma unroll
  for (int rg = 0; rg < 2; ++rg)
#pragma unroll
    for (int cg = 0; cg < 2; ++cg)
#pragma unroll
      for (int j = 0; j < 4; ++j) {
        int row = rg * 16 + q * 4 + j;
        out[(size_t)(brow + row) * DDIM + nt * 256 + wv * 32 + cg * 16 + r] =
            (acc1[rg][cg][j] + invsS[row] * acc2[rg][cg][j]) * rdegS[row];
      }
#undef ISSUE_A
#undef LOADB2
#undef XFORM
#undef MFMA_TILE2
#undef SYNC
}

extern "C" void kernel_launch(void* const* d_in, const int* in_sizes, int n_in,
                              void* d_out, int out_size, void* d_ws, size_t ws_size,
                              hipStream_t stream) {
  const float* cur = (const float*)d_in[0];          // [8192, 512] fp32
  const float* incm = (const float*)d_in[1];         // [8192, 8192] fp32
  float* out = (float*)d_out;                        // [8192, 512] fp32
  unsigned char* ws = (unsigned char*)d_ws;

  unsigned char* bws = ws;                           // 8MB B chunks
  float* rdeg = (float*)(ws + 8388608);              // 32KB
  unsigned char* aprime = ws + 8421376;              // 128MB A' chunks
  const size_t need = 8421376ull + 134217728ull;     // 142,639,104

  hipLaunchKernelGGL(bprep_kernel, dim3((NROWS * DDIM / 8) / 256), dim3(256), 0, stream,
                     cur, bws);
  if (ws_size >= need) {
    hipLaunchKernelGGL(prep_kernel, dim3(NROWS / 4), dim3(1024), 0, stream,
                       incm, rdeg, aprime);
    hipLaunchKernelGGL(gemm_fast, dim3(512), dim3(512), 0, stream,
                       aprime, bws, rdeg, out);
  } else {
    hipLaunchKernelGGL(gemm_dual, dim3(512), dim3(512), 0, stream, incm, bws, out);
  }
}